// Round 1
// baseline (874.829 us; speedup 1.0000x reference)
//
#include <hip/hip_runtime.h>

typedef __attribute__((ext_vector_type(8))) short short8;
typedef __attribute__((ext_vector_type(4))) float f32x4;

constexpr int B_ = 4, S_ = 2048, E_ = 1024, H_ = 8, D_ = 256;
constexpr int HD_ = H_ * D_;   // 2048
constexpr int BS_ = B_ * S_;   // 8192
constexpr int BH_ = B_ * H_;   // 32
constexpr float INV_SQRT_E = 0.03125f;  // 1/sqrt(1024)

__device__ __forceinline__ unsigned short f2bf(float f) {
    union { float f; unsigned u; } x; x.f = f;
    unsigned r = (x.u + 0x7fffu + ((x.u >> 16) & 1u)) >> 16;
    return (unsigned short)r;
}

__device__ __forceinline__ void gl_lds16(const void* g, void* lds) {
    __builtin_amdgcn_global_load_lds((const __attribute__((address_space(1))) void*)g,
                                     (__attribute__((address_space(3))) void*)lds, 16, 0, 0);
}

// ---------------- cast A fp32 -> bf16 (vectorized) ----------------
__global__ __launch_bounds__(256) void cast_k(const float* __restrict__ src,
                                              unsigned short* __restrict__ dst, int n4) {
    int i = blockIdx.x * 256 + threadIdx.x;
    if (i >= n4) return;
    float4 v = reinterpret_cast<const float4*>(src)[i];
    ushort4 o;
    o.x = f2bf(v.x); o.y = f2bf(v.y); o.z = f2bf(v.z); o.w = f2bf(v.w);
    reinterpret_cast<ushort4*>(dst)[i] = o;
}

// ------------- batched transpose+cast: (bt,R,C) f32 -> (bt,C,R) bf16 -------------
__global__ __launch_bounds__(256) void tcast_k(const float* __restrict__ src,
                                               unsigned short* __restrict__ dst, int R, int C) {
    __shared__ float tile[32][33];
    int b = blockIdx.z;
    const float* s = src + (size_t)b * R * C;
    unsigned short* d = dst + (size_t)b * R * C;
    int c0 = blockIdx.x * 32, r0 = blockIdx.y * 32;
    int tx = threadIdx.x, ty = threadIdx.y;
#pragma unroll
    for (int i = 0; i < 4; ++i)
        tile[ty + i * 8][tx] = s[(size_t)(r0 + ty + i * 8) * C + c0 + tx];
    __syncthreads();
#pragma unroll
    for (int i = 0; i < 4; ++i)
        d[(size_t)(c0 + ty + i * 8) * R + r0 + tx] = f2bf(tile[tx][ty + i * 8]);
}

// ------------- bf16 transpose: (BH,S,D) -> (BH,D,S) -------------
__global__ __launch_bounds__(256) void tbf_k(const unsigned short* __restrict__ src,
                                             unsigned short* __restrict__ dst) {
    __shared__ unsigned short tile[32][33];
    int bh = blockIdx.z;
    int d0 = blockIdx.x * 32, s0 = blockIdx.y * 32;
    int tx = threadIdx.x, ty = threadIdx.y;
#pragma unroll
    for (int i = 0; i < 4; ++i)
        tile[ty + i * 8][tx] = src[((size_t)bh * S_ + s0 + ty + i * 8) * D_ + d0 + tx];
    __syncthreads();
#pragma unroll
    for (int i = 0; i < 4; ++i)
        dst[((size_t)bh * D_ + d0 + ty + i * 8) * S_ + s0 + tx] = tile[tx][ty + i * 8];
}

// ------------- QKV GEMM: A(BS,E) x Wt(n=h*D+d)[k=e] -> relu(+bias) -> (B,H,S,D) bf16 -------------
__global__ __launch_bounds__(256) void gemm_qkv_k(const unsigned short* __restrict__ A,
                                                  const unsigned short* __restrict__ Bt,
                                                  const float* __restrict__ bias,
                                                  unsigned short* __restrict__ out) {
    __shared__ __align__(16) unsigned short As[128 * 32];
    __shared__ __align__(16) unsigned short Bs[128 * 32];
    const int tid = threadIdx.x;
    const int wave = tid >> 6, lane = tid & 63;
    const int quad = lane >> 4, l15 = lane & 15;
    const int wm = wave >> 1, wn = wave & 1;
    const int m0 = blockIdx.y * 128, n0 = blockIdx.x * 128;
    const int c1 = tid, c2 = tid + 256;
    const int r1 = c1 >> 2, kc1 = (c1 & 3) * 8;
    const int r2 = c2 >> 2, kc2 = (c2 & 3) * 8;
    char* aB1 = (char*)As + wave * 1024; char* aB2 = aB1 + 4096;
    char* bB1 = (char*)Bs + wave * 1024; char* bB2 = bB1 + 4096;
    const unsigned short* a1 = A + (size_t)(m0 + r1) * E_ + kc1;
    const unsigned short* a2 = A + (size_t)(m0 + r2) * E_ + kc2;
    const unsigned short* b1 = Bt + (size_t)(n0 + r1) * E_ + kc1;
    const unsigned short* b2 = Bt + (size_t)(n0 + r2) * E_ + kc2;
    f32x4 acc[4][4] = {};
    for (int k0 = 0; k0 < E_; k0 += 32) {
        __syncthreads();
        gl_lds16(a1 + k0, aB1);
        gl_lds16(a2 + k0, aB2);
        gl_lds16(b1 + k0, bB1);
        gl_lds16(b2 + k0, bB2);
        __syncthreads();
        short8 af[4], bf[4];
        const short* Ass = (const short*)As;
        const short* Bss = (const short*)Bs;
#pragma unroll
        for (int f = 0; f < 4; ++f) {
            af[f] = *(const short8*)&Ass[(wm * 64 + f * 16 + l15) * 32 + quad * 8];
            bf[f] = *(const short8*)&Bss[(wn * 64 + f * 16 + l15) * 32 + quad * 8];
        }
#pragma unroll
        for (int fm = 0; fm < 4; ++fm)
#pragma unroll
            for (int fn = 0; fn < 4; ++fn)
                acc[fm][fn] = __builtin_amdgcn_mfma_f32_16x16x32_bf16(af[fm], bf[fn], acc[fm][fn], 0, 0, 0);
    }
#pragma unroll
    for (int fm = 0; fm < 4; ++fm) {
        int mbase = m0 + wm * 64 + fm * 16 + quad * 4;
#pragma unroll
        for (int fn = 0; fn < 4; ++fn) {
            int n = n0 + wn * 64 + fn * 16 + l15;
            int h = n >> 8, d = n & 255;
            float bv = bias[n];
#pragma unroll
            for (int r = 0; r < 4; ++r) {
                int m = mbase + r;
                int b = m >> 11, s = m & 2047;
                float v = fmaxf(acc[fm][fn][r] + bv, 0.0f);
                out[((size_t)(b * H_ + h) * S_ + s) * D_ + d] = f2bf(v);
            }
        }
    }
}

// ------------- output GEMM: Zall(BS,HD) x Wzt(n)[k] + bZ -> fp32 (BS,E) -------------
__global__ __launch_bounds__(256) void gemm_out_k(const unsigned short* __restrict__ A,
                                                  const unsigned short* __restrict__ Bt,
                                                  const float* __restrict__ bias,
                                                  float* __restrict__ out) {
    __shared__ __align__(16) unsigned short As[128 * 32];
    __shared__ __align__(16) unsigned short Bs[128 * 32];
    const int tid = threadIdx.x;
    const int wave = tid >> 6, lane = tid & 63;
    const int quad = lane >> 4, l15 = lane & 15;
    const int wm = wave >> 1, wn = wave & 1;
    const int m0 = blockIdx.y * 128, n0 = blockIdx.x * 128;
    const int c1 = tid, c2 = tid + 256;
    const int r1 = c1 >> 2, kc1 = (c1 & 3) * 8;
    const int r2 = c2 >> 2, kc2 = (c2 & 3) * 8;
    char* aB1 = (char*)As + wave * 1024; char* aB2 = aB1 + 4096;
    char* bB1 = (char*)Bs + wave * 1024; char* bB2 = bB1 + 4096;
    const unsigned short* a1 = A + (size_t)(m0 + r1) * HD_ + kc1;
    const unsigned short* a2 = A + (size_t)(m0 + r2) * HD_ + kc2;
    const unsigned short* b1 = Bt + (size_t)(n0 + r1) * HD_ + kc1;
    const unsigned short* b2 = Bt + (size_t)(n0 + r2) * HD_ + kc2;
    f32x4 acc[4][4] = {};
    for (int k0 = 0; k0 < HD_; k0 += 32) {
        __syncthreads();
        gl_lds16(a1 + k0, aB1);
        gl_lds16(a2 + k0, aB2);
        gl_lds16(b1 + k0, bB1);
        gl_lds16(b2 + k0, bB2);
        __syncthreads();
        short8 af[4], bf[4];
        const short* Ass = (const short*)As;
        const short* Bss = (const short*)Bs;
#pragma unroll
        for (int f = 0; f < 4; ++f) {
            af[f] = *(const short8*)&Ass[(wm * 64 + f * 16 + l15) * 32 + quad * 8];
            bf[f] = *(const short8*)&Bss[(wn * 64 + f * 16 + l15) * 32 + quad * 8];
        }
#pragma unroll
        for (int fm = 0; fm < 4; ++fm)
#pragma unroll
            for (int fn = 0; fn < 4; ++fn)
                acc[fm][fn] = __builtin_amdgcn_mfma_f32_16x16x32_bf16(af[fm], bf[fn], acc[fm][fn], 0, 0, 0);
    }
#pragma unroll
    for (int fm = 0; fm < 4; ++fm) {
        int mbase = m0 + wm * 64 + fm * 16 + quad * 4;
#pragma unroll
        for (int fn = 0; fn < 4; ++fn) {
            int n = n0 + wn * 64 + fn * 16 + l15;
            float bv = bias[n];
#pragma unroll
            for (int r = 0; r < 4; ++r)
                out[(size_t)(mbase + r) * E_ + n] = acc[fm][fn][r] + bv;
        }
    }
}

// ------------- pass A: column stats M[t], L[t] over s (first softmax axis) -------------
__global__ __launch_bounds__(256) void colstats_k(const unsigned short* __restrict__ Q,
                                                  const unsigned short* __restrict__ K,
                                                  float* __restrict__ Mcol, float* __restrict__ Lcol) {
    __shared__ __align__(16) unsigned short As[128 * 32];  // K rows (t)
    __shared__ __align__(16) unsigned short Bs[128 * 32];  // Q rows (s)
    __shared__ float partM[2][128], partL[2][128];
    const int tid = threadIdx.x;
    const int wave = tid >> 6, lane = tid & 63;
    const int quad = lane >> 4, l15 = lane & 15;
    const int wm = wave >> 1, wn = wave & 1;
    const int bh = blockIdx.y;
    const int t0 = blockIdx.x * 128;
    const unsigned short* Kh = K + (size_t)bh * S_ * D_;
    const unsigned short* Qh = Q + (size_t)bh * S_ * D_;
    const int c1 = tid, c2 = tid + 256;
    const int r1 = c1 >> 2, kc1 = (c1 & 3) * 8;
    const int r2 = c2 >> 2, kc2 = (c2 & 3) * 8;
    char* aB1 = (char*)As + wave * 1024; char* aB2 = aB1 + 4096;
    char* bB1 = (char*)Bs + wave * 1024; char* bB2 = bB1 + 4096;
    float rm[4][4], rl[4][4];
#pragma unroll
    for (int i = 0; i < 4; ++i)
#pragma unroll
        for (int j = 0; j < 4; ++j) { rm[i][j] = -1e30f; rl[i][j] = 0.f; }
    for (int s0 = 0; s0 < S_; s0 += 128) {
        f32x4 acc[4][4] = {};
        for (int k0 = 0; k0 < D_; k0 += 32) {
            __syncthreads();
            gl_lds16(Kh + (size_t)(t0 + r1) * D_ + k0 + kc1, aB1);
            gl_lds16(Kh + (size_t)(t0 + r2) * D_ + k0 + kc2, aB2);
            gl_lds16(Qh + (size_t)(s0 + r1) * D_ + k0 + kc1, bB1);
            gl_lds16(Qh + (size_t)(s0 + r2) * D_ + k0 + kc2, bB2);
            __syncthreads();
            short8 af[4], bf[4];
            const short* Ass = (const short*)As;
            const short* Bss = (const short*)Bs;
#pragma unroll
            for (int f = 0; f < 4; ++f) {
                af[f] = *(const short8*)&Ass[(wm * 64 + f * 16 + l15) * 32 + quad * 8];
                bf[f] = *(const short8*)&Bss[(wn * 64 + f * 16 + l15) * 32 + quad * 8];
            }
#pragma unroll
            for (int fm = 0; fm < 4; ++fm)
#pragma unroll
                for (int fn = 0; fn < 4; ++fn)
                    acc[fm][fn] = __builtin_amdgcn_mfma_f32_16x16x32_bf16(af[fm], bf[fn], acc[fm][fn], 0, 0, 0);
        }
        // reduce over s (cols of the tile): max then sumexp, online merge
#pragma unroll
        for (int fm = 0; fm < 4; ++fm)
#pragma unroll
            for (int r = 0; r < 4; ++r) {
                float m4 = fmaxf(fmaxf(acc[fm][0][r], acc[fm][1][r]),
                                 fmaxf(acc[fm][2][r], acc[fm][3][r]));
                m4 = fmaxf(m4, __shfl_xor(m4, 1));
                m4 = fmaxf(m4, __shfl_xor(m4, 2));
                m4 = fmaxf(m4, __shfl_xor(m4, 4));
                m4 = fmaxf(m4, __shfl_xor(m4, 8));
                float scmax = m4 * INV_SQRT_E;
                float s4 = 0.f;
#pragma unroll
                for (int fn = 0; fn < 4; ++fn)
                    s4 += __expf(acc[fm][fn][r] * INV_SQRT_E - scmax);
                s4 += __shfl_xor(s4, 1);
                s4 += __shfl_xor(s4, 2);
                s4 += __shfl_xor(s4, 4);
                s4 += __shfl_xor(s4, 8);
                float om = rm[fm][r];
                float nm = fmaxf(om, scmax);
                rl[fm][r] = rl[fm][r] * __expf(om - nm) + s4 * __expf(scmax - nm);
                rm[fm][r] = nm;
            }
    }
    __syncthreads();
    if (l15 == 0) {
#pragma unroll
        for (int fm = 0; fm < 4; ++fm)
#pragma unroll
            for (int r = 0; r < 4; ++r) {
                int row = wm * 64 + fm * 16 + quad * 4 + r;
                partM[wn][row] = rm[fm][r];
                partL[wn][row] = rl[fm][r];
            }
    }
    __syncthreads();
    if (tid < 128) {
        float m0v = partM[0][tid], m1v = partM[1][tid];
        float nm = fmaxf(m0v, m1v);
        float L = partL[0][tid] * __expf(m0v - nm) + partL[1][tid] * __expf(m1v - nm);
        Mcol[(size_t)bh * S_ + t0 + tid] = nm;
        Lcol[(size_t)bh * S_ + t0 + tid] = L;
    }
}

// ------------- pass B: flash over t with precomputed column stats -------------
__global__ __launch_bounds__(256) void flash_k(const unsigned short* __restrict__ Q,
                                               const unsigned short* __restrict__ K,
                                               const unsigned short* __restrict__ Vt,
                                               const float* __restrict__ Mcol,
                                               const float* __restrict__ Lcol,
                                               unsigned short* __restrict__ Zall) {
    __shared__ __align__(16) unsigned short Qs[64 * 32];
    __shared__ __align__(16) unsigned short Ks[128 * 32];
    __shared__ __align__(16) unsigned short Ps[64 * 136];  // +8 pad: 2-way (free) banks
    __shared__ float rsum[64];
    const int tid = threadIdx.x;
    const int wave = tid >> 6, lane = tid & 63;
    const int quad = lane >> 4, l15 = lane & 15;
    const int bh = blockIdx.y;
    const int bb = bh >> 3, hh = bh & 7;
    const int s0 = blockIdx.x * 64;
    const unsigned short* Qh = Q + (size_t)bh * S_ * D_;
    const unsigned short* Kh = K + (size_t)bh * S_ * D_;
    const unsigned short* Vh = Vt + (size_t)bh * D_ * S_;
    const float* Mc = Mcol + (size_t)bh * S_;
    const float* Lc = Lcol + (size_t)bh * S_;
    const int c1 = tid, c2 = tid + 256;
    const int rq = c1 >> 2, kq = (c1 & 3) * 8;
    const int rk2 = c2 >> 2, kk2 = (c2 & 3) * 8;
    char* qB = (char*)Qs + wave * 1024;
    char* kB1 = (char*)Ks + wave * 1024; char* kB2 = kB1 + 4096;
    f32x4 zacc[4][4] = {};
    float rs[4][4] = {};
    for (int t0 = 0; t0 < S_; t0 += 128) {
        f32x4 sacc[4][2] = {};
        for (int k0 = 0; k0 < D_; k0 += 32) {
            __syncthreads();
            gl_lds16(Qh + (size_t)(s0 + rq) * D_ + k0 + kq, qB);
            gl_lds16(Kh + (size_t)(t0 + rq) * D_ + k0 + kq, kB1);
            gl_lds16(Kh + (size_t)(t0 + rk2) * D_ + k0 + kk2, kB2);
            __syncthreads();
            short8 af[4], bf2[2];
            const short* Qss = (const short*)Qs;
            const short* Kss = (const short*)Ks;
#pragma unroll
            for (int f = 0; f < 4; ++f)
                af[f] = *(const short8*)&Qss[(f * 16 + l15) * 32 + quad * 8];
#pragma unroll
            for (int f = 0; f < 2; ++f)
                bf2[f] = *(const short8*)&Kss[(wave * 32 + f * 16 + l15) * 32 + quad * 8];
#pragma unroll
            for (int fm = 0; fm < 4; ++fm)
#pragma unroll
                for (int fn = 0; fn < 2; ++fn)
                    sacc[fm][fn] = __builtin_amdgcn_mfma_f32_16x16x32_bf16(af[fm], bf2[fn], sacc[fm][fn], 0, 0, 0);
        }
        __syncthreads();  // previous PV done reading Ps
        float mcv[2], liv[2];
#pragma unroll
        for (int fn = 0; fn < 2; ++fn) {
            int tc = t0 + wave * 32 + fn * 16 + l15;
            mcv[fn] = Mc[tc];
            liv[fn] = 1.0f / Lc[tc];
        }
#pragma unroll
        for (int fm = 0; fm < 4; ++fm)
#pragma unroll
            for (int r = 0; r < 4; ++r)
#pragma unroll
                for (int fn = 0; fn < 2; ++fn) {
                    float sc = sacc[fm][fn][r] * INV_SQRT_E;
                    float a1 = __expf(sc - mcv[fn]) * liv[fn];  // first softmax, in [0,1]
                    float e = __expf(a1);                        // second softmax numerator
                    rs[fm][r] += e;
                    Ps[(fm * 16 + quad * 4 + r) * 136 + wave * 32 + fn * 16 + l15] = f2bf(e);
                }
        __syncthreads();
        // PV: A = P (LDS), B = Vt rows straight from global/L2
#pragma unroll
        for (int kk = 0; kk < 4; ++kk) {
            short8 pa[4], vb[4];
            const short* Pss = (const short*)Ps;
#pragma unroll
            for (int fm = 0; fm < 4; ++fm)
                pa[fm] = *(const short8*)&Pss[(fm * 16 + l15) * 136 + kk * 32 + quad * 8];
#pragma unroll
            for (int fn = 0; fn < 4; ++fn) {
                const unsigned short* vr =
                    Vh + (size_t)(wave * 64 + fn * 16 + l15) * S_ + t0 + kk * 32 + quad * 8;
                vb[fn] = *(const short8*)vr;
            }
#pragma unroll
            for (int fm = 0; fm < 4; ++fm)
#pragma unroll
                for (int fn = 0; fn < 4; ++fn)
                    zacc[fm][fn] = __builtin_amdgcn_mfma_f32_16x16x32_bf16(pa[fm], vb[fn], zacc[fm][fn], 0, 0, 0);
        }
    }
    // rowsum reduction + normalize + store
    __syncthreads();
    if (tid < 64) rsum[tid] = 0.f;
    __syncthreads();
    float rv[4][4];
#pragma unroll
    for (int fm = 0; fm < 4; ++fm)
#pragma unroll
        for (int r = 0; r < 4; ++r) {
            float v = rs[fm][r];
            v += __shfl_xor(v, 1); v += __shfl_xor(v, 2);
            v += __shfl_xor(v, 4); v += __shfl_xor(v, 8);
            rv[fm][r] = v;
        }
    if (l15 == 0)
#pragma unroll
        for (int fm = 0; fm < 4; ++fm)
#pragma unroll
            for (int r = 0; r < 4; ++r)
                atomicAdd(&rsum[fm * 16 + quad * 4 + r], rv[fm][r]);
    __syncthreads();
#pragma unroll
    for (int fm = 0; fm < 4; ++fm)
#pragma unroll
        for (int r = 0; r < 4; ++r) {
            int srow = fm * 16 + quad * 4 + r;
            float inv = 1.0f / rsum[srow];
#pragma unroll
            for (int fn = 0; fn < 4; ++fn) {
                int col = wave * 64 + fn * 16 + l15;
                Zall[(size_t)(bb * S_ + s0 + srow) * HD_ + hh * D_ + col] =
                    f2bf(zacc[fm][fn][r] * inv);
            }
        }
}

extern "C" void kernel_launch(void* const* d_in, const int* in_sizes, int n_in,
                              void* d_out, int out_size, void* d_ws, size_t ws_size,
                              hipStream_t stream) {
    const float* Ain = (const float*)d_in[0];
    const float* WQ = (const float*)d_in[1];
    const float* bQ = (const float*)d_in[2];
    const float* WK = (const float*)d_in[3];
    const float* bK = (const float*)d_in[4];
    const float* WV = (const float*)d_in[5];
    const float* bV = (const float*)d_in[6];
    const float* WZ = (const float*)d_in[7];
    const float* bZ = (const float*)d_in[8];
    float* out = (float*)d_out;

    char* ws = (char*)d_ws;
    size_t off = 0;
    auto alloc = [&](size_t bytes) {
        char* p = ws + off;
        off += (bytes + 255) & ~(size_t)255;
        return p;
    };
    unsigned short* Abf = (unsigned short*)alloc((size_t)BS_ * E_ * 2);
    unsigned short* Wqt = (unsigned short*)alloc((size_t)H_ * D_ * E_ * 2);
    unsigned short* Wkt = (unsigned short*)alloc((size_t)H_ * D_ * E_ * 2);
    unsigned short* Wvt = (unsigned short*)alloc((size_t)H_ * D_ * E_ * 2);
    unsigned short* Wzt = (unsigned short*)alloc((size_t)E_ * HD_ * 2);
    unsigned short* Qb = (unsigned short*)alloc((size_t)BH_ * S_ * D_ * 2);
    unsigned short* Kb = (unsigned short*)alloc((size_t)BH_ * S_ * D_ * 2);
    unsigned short* Vb = (unsigned short*)alloc((size_t)BH_ * S_ * D_ * 2);
    unsigned short* Vtb = (unsigned short*)alloc((size_t)BH_ * S_ * D_ * 2);
    unsigned short* Zb = (unsigned short*)alloc((size_t)BS_ * HD_ * 2);
    float* Mc = (float*)alloc((size_t)BH_ * S_ * 4);
    float* Lc = (float*)alloc((size_t)BH_ * S_ * 4);

    dim3 tb(32, 8);
    cast_k<<<(BS_ * E_ / 4 + 255) / 256, 256, 0, stream>>>(Ain, Abf, BS_ * E_ / 4);
    tcast_k<<<dim3(D_ / 32, E_ / 32, H_), tb, 0, stream>>>(WQ, Wqt, E_, D_);
    tcast_k<<<dim3(D_ / 32, E_ / 32, H_), tb, 0, stream>>>(WK, Wkt, E_, D_);
    tcast_k<<<dim3(D_ / 32, E_ / 32, H_), tb, 0, stream>>>(WV, Wvt, E_, D_);
    tcast_k<<<dim3(E_ / 32, HD_ / 32, 1), tb, 0, stream>>>(WZ, Wzt, HD_, E_);

    gemm_qkv_k<<<dim3(HD_ / 128, BS_ / 128), 256, 0, stream>>>(Abf, Wqt, bQ, Qb);
    gemm_qkv_k<<<dim3(HD_ / 128, BS_ / 128), 256, 0, stream>>>(Abf, Wkt, bK, Kb);
    gemm_qkv_k<<<dim3(HD_ / 128, BS_ / 128), 256, 0, stream>>>(Abf, Wvt, bV, Vb);

    tbf_k<<<dim3(D_ / 32, S_ / 32, BH_), tb, 0, stream>>>(Vb, Vtb);

    colstats_k<<<dim3(S_ / 128, BH_), 256, 0, stream>>>(Qb, Kb, Mc, Lc);
    flash_k<<<dim3(S_ / 64, BH_), 256, 0, stream>>>(Qb, Kb, Vtb, Mc, Lc, Zb);

    gemm_out_k<<<dim3(E_ / 128, BS_ / 128), 256, 0, stream>>>(Zb, Wzt, bZ, out);
}